// Round 11
// baseline (69.232 us; speedup 1.0000x reference)
//
#include <hip/hip_runtime.h>
#include <math.h>

#define NNODE 120000
#define DDIM  128
#define SS    100
#define NNEGS 50
#define ROWS_A 1600    // anchor/positive rows per type: slice(4) x idset(4) x 100
#define ROWS_N 20000   // cross-neg rows per type: vl(4) x s(100) x n(50)
#define TOTAL_ROWS 43200
#define BLK_ROWS 256
#define NBLK 169                             // 169 x 256 = 43264 (pad clamps)
#define ZPAD_ROWS 43264
#define INV_TEMP 2.0f

typedef unsigned short ushort_t;
typedef __attribute__((ext_vector_type(8))) short bf16x8;
typedef __attribute__((ext_vector_type(8))) unsigned short u16x8;
typedef __attribute__((ext_vector_type(4))) float f32x4;

__device__ __forceinline__ ushort_t f2b(float f) {
  unsigned u = __builtin_bit_cast(unsigned, f);
  u += 0x7fffu + ((u >> 16) & 1u);           // RNE
  return (ushort_t)(u >> 16);
}
__device__ __forceinline__ float b2f(ushort_t h) {
  return __builtin_bit_cast(float, (unsigned)h << 16);
}
__device__ __forceinline__ bool idx_is64(const void* p) {
  const unsigned* q = (const unsigned*)p;
  return (q[1] | q[3] | q[5] | q[7]) == 0u;
}
__device__ __forceinline__ int ld_idx(const void* p, int i, bool is64) {
  return is64 ? (int)((const long long*)p)[i] : ((const int*)p)[i];
}

// zrows layout (bf16 rows of 128):
//   [0,1600) A_p | [1600,3200) A_c | [3200,23200) N_pc | [23200,43200) N_cp | pad
__device__ __forceinline__ const float* row_src(
    int rid, bool is64,
    const float* emb_p, const float* emb_c,
    const void* idx_p, const void* idx_c,
    const void* nidx_p, const void* nidx_c)
{
  if (rid < 2 * ROWS_A) {
    const int typ = rid / ROWS_A;
    const int rr  = rid - typ * ROWS_A;
    const int slice = rr / 400;
    const int rem   = rr - slice * 400;          // idset*100 + s
    const int node  = ld_idx(typ ? idx_c : idx_p, rem, is64);
    return (typ ? emb_c : emb_p) + ((size_t)slice * NNODE + node) * DDIM;
  } else {
    const int r2  = rid - 2 * ROWS_A;
    const int typ = r2 / ROWS_N;
    const int rr  = r2 - typ * ROWS_N;
    const int slice = rr / (SS * NNEGS);
    const int rem   = rr - slice * (SS * NNEGS);
    const int node  = ld_idx(typ ? nidx_c : nidx_p, slice * (SS * NNEGS) + rem, is64);
    return (typ ? emb_p : emb_c) + ((size_t)slice * NNODE + node) * DDIM;
  }
}

__global__ __launch_bounds__(512, 2)
void proj_kernel(const float* __restrict__ emb_p, const float* __restrict__ emb_c,
                 const float* __restrict__ W1, const float* __restrict__ b1v,
                 const float* __restrict__ W2, const float* __restrict__ b2v,
                 const void* __restrict__ idx_p, const void* __restrict__ idx_c,
                 const void* __restrict__ nidx_p, const void* __restrict__ nidx_c,
                 ushort_t* __restrict__ zout, float* __restrict__ out)
{
  __shared__ __align__(16) ushort_t wlds[2 * 16384];          // 64 KB: W1+W2 frags
  __shared__ __align__(16) ushort_t hlds[128 * DDIM];         // 32 KB: per-tile slabs
  const int t = threadIdx.x, w = t >> 6, l = t & 63;
  const int g = l >> 4, li = l & 15;
  const bool is64 = idx_is64(idx_p);
  const int base = blockIdx.x * BLK_ROWS;
  const int r0 = w * 16;
  char* hb = (char*)hlds;

  if (blockIdx.x == 0 && t == 0) out[0] = 0.f;   // loss launches after proj completes

  // ---- issue BOTH tiles' gathers first (latency hides under W build / tile0) ----
  int rid0 = base + r0 + li;
  int rid1 = base + 128 + r0 + li;
  if (rid0 > TOTAL_ROWS - 1) rid0 = TOTAL_ROWS - 1;
  if (rid1 > TOTAL_ROWS - 1) rid1 = TOTAL_ROWS - 1;
  const float* src0 = row_src(rid0, is64, emb_p, emb_c, idx_p, idx_c, nidx_p, nidx_c);
  const float* src1 = row_src(rid1, is64, emb_p, emb_c, idx_p, idx_c, nidx_p, nidx_c);
  float4 xr0[8], xr1[8];
  #pragma unroll
  for (int kc = 0; kc < 4; ++kc) {
    xr0[2 * kc]     = *(const float4*)(src0 + kc * 32 + g * 8);
    xr0[2 * kc + 1] = *(const float4*)(src0 + kc * 32 + g * 8 + 4);
    xr1[2 * kc]     = *(const float4*)(src1 + kc * 32 + g * 8);
    xr1[2 * kc + 1] = *(const float4*)(src1 + kc * 32 + g * 8 + 4);
  }

  // ---- build W1+W2 fragments in LDS, once per block (conflict-free 16B slots) ----
  #pragma unroll
  for (int p = 0; p < 8; ++p) {
    const int s = p * 512 + t;
    const int layer = s >> 11;
    const int idx = s & 2047;
    const int lane = idx & 63, kcct = idx >> 6;
    const int kc = kcct >> 3, ct = kcct & 7;
    const float* W = layer ? W2 : W1;
    const float* wp = W + (size_t)(kc * 32 + ((lane >> 4) << 3)) * DDIM
                        + ct * 16 + (lane & 15);
    u16x8 v;
    #pragma unroll
    for (int e = 0; e < 8; ++e) v[e] = f2b(wp[(size_t)e * DDIM]);
    *(u16x8*)&wlds[(size_t)s * 8] = v;     // single linear ds_write_b128
  }
  __syncthreads();                                   // weights ready (only barrier)

  // ---- two 128-row tiles, barrier-free (slab regions are wave-private) ----
  #pragma unroll
  for (int tp = 0; tp < 2; ++tp) {
    bf16x8 afrag[4];
    #pragma unroll
    for (int kc = 0; kc < 4; ++kc) {
      const float4 xa = tp ? xr1[2 * kc] : xr0[2 * kc];
      const float4 xb = tp ? xr1[2 * kc + 1] : xr0[2 * kc + 1];
      bf16x8 af;
      af[0]=(short)f2b(xa.x); af[1]=(short)f2b(xa.y); af[2]=(short)f2b(xa.z); af[3]=(short)f2b(xa.w);
      af[4]=(short)f2b(xb.x); af[5]=(short)f2b(xb.y); af[6]=(short)f2b(xb.z); af[7]=(short)f2b(xb.w);
      afrag[kc] = af;
    }
    f32x4 acc[8];
    // layer 1: H = relu(X @ W1 + b1)
    #pragma unroll
    for (int ct = 0; ct < 8; ++ct) {
      const float bv = b1v[ct * 16 + li];
      acc[ct] = (f32x4){bv, bv, bv, bv};
    }
    #pragma unroll
    for (int kc = 0; kc < 4; ++kc)
      #pragma unroll
      for (int ct = 0; ct < 8; ++ct)
        acc[ct] = __builtin_amdgcn_mfma_f32_16x16x32_bf16(
            afrag[kc], *(const bf16x8*)&wlds[((kc * 8 + ct) * 64 + l) * 8], acc[ct], 0, 0, 0);
    // relu -> slab (XOR-swizzled; wave-private region, in-order DS per wave)
    #pragma unroll
    for (int ct = 0; ct < 8; ++ct)
      #pragma unroll
      for (int rg = 0; rg < 4; ++rg) {
        const int row = r0 + 4 * g + rg;
        const int byte = row * 256 + (ct * 16 + li) * 2;
        *(ushort_t*)(hb + (byte ^ ((row & 7) << 4))) = f2b(fmaxf(acc[ct][rg], 0.f));
      }
    // layer 2: Z = H @ W2 + b2
    #pragma unroll
    for (int ct = 0; ct < 8; ++ct) {
      const float bv = b2v[ct * 16 + li];
      acc[ct] = (f32x4){bv, bv, bv, bv};
    }
    {
      const int row = r0 + li;
      #pragma unroll
      for (int kc = 0; kc < 4; ++kc) {
        const int byte = row * 256 + kc * 64 + g * 16;
        const bf16x8 hf = *(const bf16x8*)(hb + (byte ^ ((row & 7) << 4)));
        #pragma unroll
        for (int ct = 0; ct < 8; ++ct)
          acc[ct] = __builtin_amdgcn_mfma_f32_16x16x32_bf16(
              hf, *(const bf16x8*)&wlds[16384 + ((kc * 8 + ct) * 64 + l) * 8],
              acc[ct], 0, 0, 0);
      }
    }
    // L2 norm across the 16-lane group
    float sc[4];
    #pragma unroll
    for (int rg = 0; rg < 4; ++rg) {
      float ssq = 0.f;
      #pragma unroll
      for (int ct = 0; ct < 8; ++ct) ssq += acc[ct][rg] * acc[ct][rg];
      ssq += __shfl_xor(ssq, 1);
      ssq += __shfl_xor(ssq, 2);
      ssq += __shfl_xor(ssq, 4);
      ssq += __shfl_xor(ssq, 8);
      sc[rg] = 1.f / fmaxf(sqrtf(ssq), 1e-12f);
    }
    // normalized z (bf16) -> own slab linear (own H reads already issued; in-order DS)
    #pragma unroll
    for (int ct = 0; ct < 8; ++ct)
      #pragma unroll
      for (int rg = 0; rg < 4; ++rg)
        hlds[(r0 + 4 * g + rg) * DDIM + ct * 16 + li] = f2b(acc[ct][rg] * sc[rg]);
    // coalesced 4 KB copy-out of own slab region (no barrier: wave-private)
    {
      const uint4* s4 = (const uint4*)&hlds[r0 * DDIM];
      uint4* d4 = (uint4*)(zout + (size_t)(base + tp * 128 + r0) * DDIM);
      #pragma unroll
      for (int i = 0; i < 4; ++i) d4[l + 64 * i] = s4[l + 64 * i];
    }
  }
}

// one target per lane: lane computes its full 128-dot, single reduce per wave
__global__ __launch_bounds__(192)
void loss_kernel(const ushort_t* __restrict__ zb, float* __restrict__ out)
{
  __shared__ __align__(16) float zf[DDIM];
  __shared__ float sp[3], sn[3];
  const int bid = blockIdx.x;            // type(2) x vl(4) x s(100)
  const int typ = bid / 400;
  const int rem = bid - typ * 400;
  const int vl  = rem / SS;
  const int s   = rem - vl * SS;
  const ushort_t* A  = zb + (size_t)(typ ? ROWS_A : 0) * DDIM;
  const ushort_t* Nb = zb + (size_t)(2 * ROWS_A + (typ ? ROWS_N : 0)) * DDIM;
  const ushort_t* zs = A + (size_t)((vl * 4 + vl) * SS + s) * DDIM;
  const int t = threadIdx.x, lane = t & 63, w = t >> 6;

  if (t < DDIM) zf[t] = b2f(zs[t]);
  __syncthreads();

  float e = 0.f;
  if (t < 152) {
    const ushort_t* tp;
    if (t < 3) {                                     // positives: other 3 slices
      const int k = t + (t >= vl ? 1 : 0);
      tp = A + (size_t)((k * 4 + vl) * SS + s) * DDIM;
    } else if (t < 102) {                            // within-negs, skip self
      int t2 = t - 3;
      if (t2 >= s) ++t2;
      tp = A + (size_t)((vl * 4 + vl) * SS + t2) * DDIM;
    } else {                                         // cross-negs
      tp = Nb + (size_t)((vl * SS + s) * NNEGS + (t - 102)) * DDIM;
    }
    float d0 = 0.f, d1 = 0.f, d2 = 0.f, d3 = 0.f;
    #pragma unroll
    for (int c = 0; c < 16; ++c) {
      const u16x8 tv = *(const u16x8*)(tp + c * 8);
      const float4 za = *(const float4*)&zf[c * 8];
      const float4 zc = *(const float4*)&zf[c * 8 + 4];
      d0 = fmaf(b2f(tv[0]), za.x, d0);
      d1 = fmaf(b2f(tv[1]), za.y, d1);
      d2 = fmaf(b2f(tv[2]), za.z, d2);
      d3 = fmaf(b2f(tv[3]), za.w, d3);
      d0 = fmaf(b2f(tv[4]), zc.x, d0);
      d1 = fmaf(b2f(tv[5]), zc.y, d1);
      d2 = fmaf(b2f(tv[6]), zc.z, d2);
      d3 = fmaf(b2f(tv[7]), zc.w, d3);
    }
    e = __expf(((d0 + d1) + (d2 + d3)) * INV_TEMP);
  }
  float pe = (t < 3) ? e : 0.f;
  float ne = (t < 3) ? 0.f : e;
  #pragma unroll
  for (int m = 1; m < 64; m <<= 1) {
    pe += __shfl_xor(pe, m);
    ne += __shfl_xor(ne, m);
  }
  if (lane == 0) { sp[w] = pe; sn[w] = ne; }
  __syncthreads();
  if (t == 0) {
    const float P  = sp[0] + sp[1] + sp[2];
    const float Ng = sn[0] + sn[1] + sn[2];
    atomicAdd(out, -logf(P / (P + Ng)) * (1.0f / 800.0f));
  }
}

extern "C" void kernel_launch(void* const* d_in, const int* in_sizes, int n_in,
                              void* d_out, int out_size, void* d_ws, size_t ws_size,
                              hipStream_t stream) {
  const float* emb_p = (const float*)d_in[0];
  const float* emb_c = (const float*)d_in[1];
  const float* W1    = (const float*)d_in[2];
  const float* b1    = (const float*)d_in[3];
  const float* W2    = (const float*)d_in[4];
  const float* b2    = (const float*)d_in[5];
  const void*  idx_p  = d_in[6];
  const void*  idx_c  = d_in[7];
  const void*  nidx_p = d_in[8];
  const void*  nidx_c = d_in[9];
  float* out = (float*)d_out;

  // DIAGNOSTIC ROUND: proj x3 (distinct z buffers), loss x1 on z1.
  // New - R10 = 2*P_warm + 2*disp; with R8 this splits P from L.
  ushort_t* z1 = (ushort_t*)d_ws;
  ushort_t* z2 = z1 + (size_t)ZPAD_ROWS * DDIM;
  ushort_t* z3 = z2 + (size_t)ZPAD_ROWS * DDIM;

  proj_kernel<<<NBLK, 512, 0, stream>>>(
      emb_p, emb_c, W1, b1, W2, b2, idx_p, idx_c, nidx_p, nidx_c, z1, out);
  proj_kernel<<<NBLK, 512, 0, stream>>>(
      emb_p, emb_c, W1, b1, W2, b2, idx_p, idx_c, nidx_p, nidx_c, z2, out);
  proj_kernel<<<NBLK, 512, 0, stream>>>(
      emb_p, emb_c, W1, b1, W2, b2, idx_p, idx_c, nidx_p, nidx_c, z3, out);
  loss_kernel<<<800, 192, 0, stream>>>(z1, out);
}

// Round 12
// 36.196 us; speedup vs baseline: 1.9127x; 1.9127x over previous
//
#include <hip/hip_runtime.h>
#include <math.h>

#define NNODE 120000
#define DDIM  128
#define SS    100
#define NNEGS 50
#define ROWS_A 1600    // anchor/positive rows per type: slice(4) x idset(4) x 100
#define ROWS_N 20000   // cross-neg rows per type: vl(4) x s(100) x n(50)
#define TOTAL_ROWS 43200
#define BLK_ROWS 256
#define NBLK 169                             // 169 x 256 = 43264 (pad clamps)
#define INV_TEMP 2.0f

typedef unsigned short ushort_t;
typedef __attribute__((ext_vector_type(8))) short bf16x8;
typedef __attribute__((ext_vector_type(8))) unsigned short u16x8;
typedef __attribute__((ext_vector_type(4))) float f32x4;

__device__ __forceinline__ ushort_t f2b(float f) {
  unsigned u = __builtin_bit_cast(unsigned, f);
  u += 0x7fffu + ((u >> 16) & 1u);           // RNE
  return (ushort_t)(u >> 16);
}
__device__ __forceinline__ float b2f(ushort_t h) {
  return __builtin_bit_cast(float, (unsigned)h << 16);
}
__device__ __forceinline__ bool idx_is64(const void* p) {
  const unsigned* q = (const unsigned*)p;
  return (q[1] | q[3] | q[5] | q[7]) == 0u;
}
__device__ __forceinline__ int ld_idx(const void* p, int i, bool is64) {
  return is64 ? (int)((const long long*)p)[i] : ((const int*)p)[i];
}

// zrows layout (bf16 rows of 128):
//   [0,1600) A_p | [1600,3200) A_c | [3200,23200) N_pc | [23200,43200) N_cp | pad
__device__ __forceinline__ const float* row_src(
    int rid, bool is64,
    const float* emb_p, const float* emb_c,
    const void* idx_p, const void* idx_c,
    const void* nidx_p, const void* nidx_c)
{
  if (rid < 2 * ROWS_A) {
    const int typ = rid / ROWS_A;
    const int rr  = rid - typ * ROWS_A;
    const int slice = rr / 400;
    const int rem   = rr - slice * 400;          // idset*100 + s
    const int node  = ld_idx(typ ? idx_c : idx_p, rem, is64);
    return (typ ? emb_c : emb_p) + ((size_t)slice * NNODE + node) * DDIM;
  } else {
    const int r2  = rid - 2 * ROWS_A;
    const int typ = r2 / ROWS_N;
    const int rr  = r2 - typ * ROWS_N;
    const int slice = rr / (SS * NNEGS);
    const int rem   = rr - slice * (SS * NNEGS);
    const int node  = ld_idx(typ ? nidx_c : nidx_p, slice * (SS * NNEGS) + rem, is64);
    return (typ ? emb_p : emb_c) + ((size_t)slice * NNODE + node) * DDIM;
  }
}

__global__ __launch_bounds__(512, 2)
void proj_kernel(const float* __restrict__ emb_p, const float* __restrict__ emb_c,
                 const float* __restrict__ W1, const float* __restrict__ b1v,
                 const float* __restrict__ W2, const float* __restrict__ b2v,
                 const void* __restrict__ idx_p, const void* __restrict__ idx_c,
                 const void* __restrict__ nidx_p, const void* __restrict__ nidx_c,
                 ushort_t* __restrict__ zout, float* __restrict__ out)
{
  __shared__ __align__(16) ushort_t wlds[2 * 16384];          // 64 KB: W1+W2 frags
  __shared__ __align__(16) ushort_t hlds[128 * DDIM];         // 32 KB: per-tile slabs
  const int t = threadIdx.x, w = t >> 6, l = t & 63;
  const int g = l >> 4, li = l & 15;
  const bool is64 = idx_is64(idx_p);
  const int base = blockIdx.x * BLK_ROWS;
  const int r0 = w * 16;
  char* hb = (char*)hlds;

  if (blockIdx.x == 0 && t == 0) out[0] = 0.f;   // loss launches after proj completes

  // ---- issue BOTH tiles' gathers first (latency hides under W build / tile0) ----
  int rid0 = base + r0 + li;
  int rid1 = base + 128 + r0 + li;
  if (rid0 > TOTAL_ROWS - 1) rid0 = TOTAL_ROWS - 1;
  if (rid1 > TOTAL_ROWS - 1) rid1 = TOTAL_ROWS - 1;
  const float* src0 = row_src(rid0, is64, emb_p, emb_c, idx_p, idx_c, nidx_p, nidx_c);
  const float* src1 = row_src(rid1, is64, emb_p, emb_c, idx_p, idx_c, nidx_p, nidx_c);
  float4 xr0[8], xr1[8];
  #pragma unroll
  for (int kc = 0; kc < 4; ++kc) {
    xr0[2 * kc]     = *(const float4*)(src0 + kc * 32 + g * 8);
    xr0[2 * kc + 1] = *(const float4*)(src0 + kc * 32 + g * 8 + 4);
    xr1[2 * kc]     = *(const float4*)(src1 + kc * 32 + g * 8);
    xr1[2 * kc + 1] = *(const float4*)(src1 + kc * 32 + g * 8 + 4);
  }

  // ---- build W1+W2 fragments in LDS, once per block (conflict-free 16B slots) ----
  #pragma unroll
  for (int p = 0; p < 8; ++p) {
    const int s = p * 512 + t;
    const int layer = s >> 11;
    const int idx = s & 2047;
    const int lane = idx & 63, kcct = idx >> 6;
    const int kc = kcct >> 3, ct = kcct & 7;
    const float* W = layer ? W2 : W1;
    const float* wp = W + (size_t)(kc * 32 + ((lane >> 4) << 3)) * DDIM
                        + ct * 16 + (lane & 15);
    u16x8 v;
    #pragma unroll
    for (int e = 0; e < 8; ++e) v[e] = f2b(wp[(size_t)e * DDIM]);
    *(u16x8*)&wlds[(size_t)s * 8] = v;     // single linear ds_write_b128
  }
  __syncthreads();                                   // weights ready (only barrier)

  // ---- two 128-row tiles, barrier-free (slab regions are wave-private) ----
  #pragma unroll
  for (int tp = 0; tp < 2; ++tp) {
    bf16x8 afrag[4];
    #pragma unroll
    for (int kc = 0; kc < 4; ++kc) {
      const float4 xa = tp ? xr1[2 * kc] : xr0[2 * kc];
      const float4 xb = tp ? xr1[2 * kc + 1] : xr0[2 * kc + 1];
      bf16x8 af;
      af[0]=(short)f2b(xa.x); af[1]=(short)f2b(xa.y); af[2]=(short)f2b(xa.z); af[3]=(short)f2b(xa.w);
      af[4]=(short)f2b(xb.x); af[5]=(short)f2b(xb.y); af[6]=(short)f2b(xb.z); af[7]=(short)f2b(xb.w);
      afrag[kc] = af;
    }
    f32x4 acc[8];
    // layer 1: H = relu(X @ W1 + b1)
    #pragma unroll
    for (int ct = 0; ct < 8; ++ct) {
      const float bv = b1v[ct * 16 + li];
      acc[ct] = (f32x4){bv, bv, bv, bv};
    }
    #pragma unroll
    for (int kc = 0; kc < 4; ++kc)
      #pragma unroll
      for (int ct = 0; ct < 8; ++ct)
        acc[ct] = __builtin_amdgcn_mfma_f32_16x16x32_bf16(
            afrag[kc], *(const bf16x8*)&wlds[((kc * 8 + ct) * 64 + l) * 8], acc[ct], 0, 0, 0);
    // relu -> slab (XOR-swizzled; wave-private region, in-order DS per wave)
    #pragma unroll
    for (int ct = 0; ct < 8; ++ct)
      #pragma unroll
      for (int rg = 0; rg < 4; ++rg) {
        const int row = r0 + 4 * g + rg;
        const int byte = row * 256 + (ct * 16 + li) * 2;
        *(ushort_t*)(hb + (byte ^ ((row & 7) << 4))) = f2b(fmaxf(acc[ct][rg], 0.f));
      }
    // layer 2: Z = H @ W2 + b2
    #pragma unroll
    for (int ct = 0; ct < 8; ++ct) {
      const float bv = b2v[ct * 16 + li];
      acc[ct] = (f32x4){bv, bv, bv, bv};
    }
    {
      const int row = r0 + li;
      #pragma unroll
      for (int kc = 0; kc < 4; ++kc) {
        const int byte = row * 256 + kc * 64 + g * 16;
        const bf16x8 hf = *(const bf16x8*)(hb + (byte ^ ((row & 7) << 4)));
        #pragma unroll
        for (int ct = 0; ct < 8; ++ct)
          acc[ct] = __builtin_amdgcn_mfma_f32_16x16x32_bf16(
              hf, *(const bf16x8*)&wlds[16384 + ((kc * 8 + ct) * 64 + l) * 8],
              acc[ct], 0, 0, 0);
      }
    }
    // L2 norm across the 16-lane group
    float sc[4];
    #pragma unroll
    for (int rg = 0; rg < 4; ++rg) {
      float ssq = 0.f;
      #pragma unroll
      for (int ct = 0; ct < 8; ++ct) ssq += acc[ct][rg] * acc[ct][rg];
      ssq += __shfl_xor(ssq, 1);
      ssq += __shfl_xor(ssq, 2);
      ssq += __shfl_xor(ssq, 4);
      ssq += __shfl_xor(ssq, 8);
      sc[rg] = 1.f / fmaxf(sqrtf(ssq), 1e-12f);
    }
    // normalized z (bf16) -> own slab linear (own H reads already issued; in-order DS)
    #pragma unroll
    for (int ct = 0; ct < 8; ++ct)
      #pragma unroll
      for (int rg = 0; rg < 4; ++rg)
        hlds[(r0 + 4 * g + rg) * DDIM + ct * 16 + li] = f2b(acc[ct][rg] * sc[rg]);
    // coalesced 4 KB copy-out of own slab region (no barrier: wave-private)
    {
      const uint4* s4 = (const uint4*)&hlds[r0 * DDIM];
      uint4* d4 = (uint4*)(zout + (size_t)(base + tp * 128 + r0) * DDIM);
      #pragma unroll
      for (int i = 0; i < 4; ++i) d4[l + 64 * i] = s4[l + 64 * i];
    }
  }
}

// Coalesced loss: 8 lanes per target row, each lane owns 32 contiguous bytes.
// lane = tgt_sub(3b) | eg(3b); anchor held in registers; 5 unrolled passes.
__global__ __launch_bounds__(256)
void loss_kernel(const ushort_t* __restrict__ zb, float* __restrict__ out)
{
  __shared__ float sp[4], sn[4];
  const int bid = blockIdx.x;            // type(2) x vl(4) x s(100)
  const int typ = bid / 400;
  const int rem = bid - typ * 400;
  const int vl  = rem / SS;
  const int s   = rem - vl * SS;
  const ushort_t* A  = zb + (size_t)(typ ? ROWS_A : 0) * DDIM;
  const ushort_t* Nb = zb + (size_t)(2 * ROWS_A + (typ ? ROWS_N : 0)) * DDIM;
  const ushort_t* zs = A + (size_t)((vl * 4 + vl) * SS + s) * DDIM;
  const int t = threadIdx.x, l = t & 63, w = t >> 6;
  const int tsub = l >> 3, eg = l & 7;

  // anchor slice (16 elems) in registers, straight from global (no LDS, no barrier)
  float zr[16];
  {
    const u16x8 v0 = *(const u16x8*)(zs + eg * 16);
    const u16x8 v1 = *(const u16x8*)(zs + eg * 16 + 8);
    #pragma unroll
    for (int j = 0; j < 8; ++j) { zr[j] = b2f(v0[j]); zr[j + 8] = b2f(v1[j]); }
  }

  float pe = 0.f, ne = 0.f;
  #pragma unroll
  for (int pass = 0; pass < 5; ++pass) {
    const int tt = pass * 32 + w * 8 + tsub;
    float d = 0.f;
    bool act = (tt < 152);
    if (act) {
      const ushort_t* tp;
      if (tt < 3) {                                    // positives: other 3 slices
        const int k = tt + (tt >= vl ? 1 : 0);
        tp = A + (size_t)((k * 4 + vl) * SS + s) * DDIM;
      } else if (tt < 102) {                           // within-negs, skip self
        int t2 = tt - 3;
        if (t2 >= s) ++t2;
        tp = A + (size_t)((vl * 4 + vl) * SS + t2) * DDIM;
      } else {                                         // cross-negs
        tp = Nb + (size_t)((vl * SS + s) * NNEGS + (tt - 102)) * DDIM;
      }
      const u16x8 x0 = *(const u16x8*)(tp + eg * 16);
      const u16x8 x1 = *(const u16x8*)(tp + eg * 16 + 8);
      #pragma unroll
      for (int j = 0; j < 8; ++j) {
        d = fmaf(b2f(x0[j]), zr[j], d);
        d = fmaf(b2f(x1[j]), zr[j + 8], d);
      }
    }
    // reduce over the 8 eg lanes (butterfly: all 8 end with the full dot)
    d += __shfl_xor(d, 1);
    d += __shfl_xor(d, 2);
    d += __shfl_xor(d, 4);
    const float e = act ? __expf(d * INV_TEMP) : 0.f;
    if (tt < 3) pe += e; else ne += e;
  }
  // reduce across the 8 target groups (each group's 8 lanes hold identical values)
  pe += __shfl_xor(pe, 8);  ne += __shfl_xor(ne, 8);
  pe += __shfl_xor(pe, 16); ne += __shfl_xor(ne, 16);
  pe += __shfl_xor(pe, 32); ne += __shfl_xor(ne, 32);
  if (l == 0) { sp[w] = pe; sn[w] = ne; }
  __syncthreads();
  if (t == 0) {
    const float P  = sp[0] + sp[1] + sp[2] + sp[3];
    const float Ng = sn[0] + sn[1] + sn[2] + sn[3];
    atomicAdd(out, -logf(P / (P + Ng)) * (1.0f / 800.0f));
  }
}

extern "C" void kernel_launch(void* const* d_in, const int* in_sizes, int n_in,
                              void* d_out, int out_size, void* d_ws, size_t ws_size,
                              hipStream_t stream) {
  const float* emb_p = (const float*)d_in[0];
  const float* emb_c = (const float*)d_in[1];
  const float* W1    = (const float*)d_in[2];
  const float* b1    = (const float*)d_in[3];
  const float* W2    = (const float*)d_in[4];
  const float* b2    = (const float*)d_in[5];
  const void*  idx_p  = d_in[6];
  const void*  idx_c  = d_in[7];
  const void*  nidx_p = d_in[8];
  const void*  nidx_c = d_in[9];
  float* out = (float*)d_out;
  ushort_t* zrows = (ushort_t*)d_ws;

  proj_kernel<<<NBLK, 512, 0, stream>>>(
      emb_p, emb_c, W1, b1, W2, b2, idx_p, idx_c, nidx_p, nidx_c, zrows, out);
  loss_kernel<<<800, 256, 0, stream>>>(zrows, out);
}

// Round 13
// 36.033 us; speedup vs baseline: 1.9213x; 1.0045x over previous
//
#include <hip/hip_runtime.h>
#include <math.h>

#define NNODE 120000
#define DDIM  128
#define SS    100
#define NNEGS 50
#define ROWS_A 1600    // anchor/positive rows per type: slice(4) x idset(4) x 100
#define ROWS_N 20000   // cross-neg rows per type: vl(4) x s(100) x n(50)
#define TOTAL_ROWS 43200
#define BLK_ROWS 256
#define NBLK 169                             // 169 x 256 = 43264 (pad clamps)
#define INV_TEMP 2.0f

typedef unsigned short ushort_t;
typedef __attribute__((ext_vector_type(8))) short bf16x8;
typedef __attribute__((ext_vector_type(8))) unsigned short u16x8;
typedef __attribute__((ext_vector_type(4))) float f32x4;

__device__ __forceinline__ ushort_t f2b(float f) {
  unsigned u = __builtin_bit_cast(unsigned, f);
  u += 0x7fffu + ((u >> 16) & 1u);           // RNE
  return (ushort_t)(u >> 16);
}
__device__ __forceinline__ float b2f(ushort_t h) {
  return __builtin_bit_cast(float, (unsigned)h << 16);
}
__device__ __forceinline__ bool idx_is64(const void* p) {
  const unsigned* q = (const unsigned*)p;
  return (q[1] | q[3] | q[5] | q[7]) == 0u;
}
__device__ __forceinline__ int ld_idx(const void* p, int i, bool is64) {
  return is64 ? (int)((const long long*)p)[i] : ((const int*)p)[i];
}

// zrows layout (bf16 rows of 128):
//   [0,1600) A_p | [1600,3200) A_c | [3200,23200) N_pc | [23200,43200) N_cp | pad
__device__ __forceinline__ const float* row_src(
    int rid, bool is64,
    const float* emb_p, const float* emb_c,
    const void* idx_p, const void* idx_c,
    const void* nidx_p, const void* nidx_c)
{
  if (rid < 2 * ROWS_A) {
    const int typ = rid / ROWS_A;
    const int rr  = rid - typ * ROWS_A;
    const int slice = rr / 400;
    const int rem   = rr - slice * 400;          // idset*100 + s
    const int node  = ld_idx(typ ? idx_c : idx_p, rem, is64);
    return (typ ? emb_c : emb_p) + ((size_t)slice * NNODE + node) * DDIM;
  } else {
    const int r2  = rid - 2 * ROWS_A;
    const int typ = r2 / ROWS_N;
    const int rr  = r2 - typ * ROWS_N;
    const int slice = rr / (SS * NNEGS);
    const int rem   = rr - slice * (SS * NNEGS);
    const int node  = ld_idx(typ ? nidx_c : nidx_p, slice * (SS * NNEGS) + rem, is64);
    return (typ ? emb_p : emb_c) + ((size_t)slice * NNODE + node) * DDIM;
  }
}

__global__ __launch_bounds__(512, 2)
void proj_kernel(const float* __restrict__ emb_p, const float* __restrict__ emb_c,
                 const float* __restrict__ W1, const float* __restrict__ b1v,
                 const float* __restrict__ W2, const float* __restrict__ b2v,
                 const void* __restrict__ idx_p, const void* __restrict__ idx_c,
                 const void* __restrict__ nidx_p, const void* __restrict__ nidx_c,
                 ushort_t* __restrict__ zout, float* __restrict__ out)
{
  __shared__ __align__(16) ushort_t wlds[2 * 16384];          // 64 KB: W1+W2 frags
  __shared__ __align__(16) ushort_t slab[BLK_ROWS * DDIM];    // 64 KB: 256-row slab
  const int t = threadIdx.x, w = t >> 6, l = t & 63;
  const int g = l >> 4, li = l & 15;
  const bool is64 = idx_is64(idx_p);
  const int base = blockIdx.x * BLK_ROWS;
  const int ra = w * 32 + li;                // sample-group A row (block-local)
  const int rb = ra + 16;                    // sample-group B row
  char* hb = (char*)slab;

  if (blockIdx.x == 0 && t == 0) out[0] = 0.f;   // loss launches after proj completes

  // ---- issue both sample-groups' gathers first ----
  int rida = base + ra, ridb = base + rb;
  if (rida > TOTAL_ROWS - 1) rida = TOTAL_ROWS - 1;
  if (ridb > TOTAL_ROWS - 1) ridb = TOTAL_ROWS - 1;
  const float* sa = row_src(rida, is64, emb_p, emb_c, idx_p, idx_c, nidx_p, nidx_c);
  const float* sb = row_src(ridb, is64, emb_p, emb_c, idx_p, idx_c, nidx_p, nidx_c);
  bf16x8 afa[4], afb[4];
  #pragma unroll
  for (int kc = 0; kc < 4; ++kc) {
    const float4 a0 = *(const float4*)(sa + kc * 32 + g * 8);
    const float4 a1 = *(const float4*)(sa + kc * 32 + g * 8 + 4);
    const float4 b0 = *(const float4*)(sb + kc * 32 + g * 8);
    const float4 b1 = *(const float4*)(sb + kc * 32 + g * 8 + 4);
    bf16x8 fa, fb;
    fa[0]=(short)f2b(a0.x); fa[1]=(short)f2b(a0.y); fa[2]=(short)f2b(a0.z); fa[3]=(short)f2b(a0.w);
    fa[4]=(short)f2b(a1.x); fa[5]=(short)f2b(a1.y); fa[6]=(short)f2b(a1.z); fa[7]=(short)f2b(a1.w);
    fb[0]=(short)f2b(b0.x); fb[1]=(short)f2b(b0.y); fb[2]=(short)f2b(b0.z); fb[3]=(short)f2b(b0.w);
    fb[4]=(short)f2b(b1.x); fb[5]=(short)f2b(b1.y); fb[6]=(short)f2b(b1.z); fb[7]=(short)f2b(b1.w);
    afa[kc] = fa; afb[kc] = fb;
  }

  // ---- build W1+W2 fragments in LDS (conflict-free 16B slots) ----
  #pragma unroll
  for (int p = 0; p < 8; ++p) {
    const int s = p * 512 + t;
    const int layer = s >> 11;
    const int idx = s & 2047;
    const int lane = idx & 63, kcct = idx >> 6;
    const int kc = kcct >> 3, ct = kcct & 7;
    const float* W = layer ? W2 : W1;
    const float* wp = W + (size_t)(kc * 32 + ((lane >> 4) << 3)) * DDIM
                        + ct * 16 + (lane & 15);
    u16x8 v;
    #pragma unroll
    for (int e = 0; e < 8; ++e) v[e] = f2b(wp[(size_t)e * DDIM]);
    *(u16x8*)&wlds[(size_t)s * 8] = v;
  }
  __syncthreads();                                   // weights ready (only barrier)

  f32x4 aa[8], ab[8];
  // ---- layer 1: H = relu(X @ W1 + b1), B-frag read once, used twice ----
  #pragma unroll
  for (int ct = 0; ct < 8; ++ct) {
    const float bv = b1v[ct * 16 + li];
    aa[ct] = (f32x4){bv, bv, bv, bv};
    ab[ct] = aa[ct];
  }
  #pragma unroll
  for (int kc = 0; kc < 4; ++kc)
    #pragma unroll
    for (int ct = 0; ct < 8; ++ct) {
      const bf16x8 bf = *(const bf16x8*)&wlds[((kc * 8 + ct) * 64 + l) * 8];
      aa[ct] = __builtin_amdgcn_mfma_f32_16x16x32_bf16(afa[kc], bf, aa[ct], 0, 0, 0);
      ab[ct] = __builtin_amdgcn_mfma_f32_16x16x32_bf16(afb[kc], bf, ab[ct], 0, 0, 0);
    }
  // relu -> slab (XOR-swizzled; wave-private 32-row region, in-order DS per wave)
  #pragma unroll
  for (int ct = 0; ct < 8; ++ct)
    #pragma unroll
    for (int rg = 0; rg < 4; ++rg) {
      const int rowa = w * 32 + 4 * g + rg;
      const int bytea = rowa * 256 + (ct * 16 + li) * 2;
      *(ushort_t*)(hb + (bytea ^ ((rowa & 7) << 4))) = f2b(fmaxf(aa[ct][rg], 0.f));
      const int rowb = rowa + 16;
      const int byteb = rowb * 256 + (ct * 16 + li) * 2;
      *(ushort_t*)(hb + (byteb ^ ((rowb & 7) << 4))) = f2b(fmaxf(ab[ct][rg], 0.f));
    }
  // ---- layer 2: Z = H @ W2 + b2, B-frag read once, used twice ----
  #pragma unroll
  for (int ct = 0; ct < 8; ++ct) {
    const float bv = b2v[ct * 16 + li];
    aa[ct] = (f32x4){bv, bv, bv, bv};
    ab[ct] = aa[ct];
  }
  #pragma unroll
  for (int kc = 0; kc < 4; ++kc) {
    const int rowa = w * 32 + li, rowb = rowa + 16;
    const int bytea = rowa * 256 + kc * 64 + g * 16;
    const int byteb = rowb * 256 + kc * 64 + g * 16;
    const bf16x8 hfa = *(const bf16x8*)(hb + (bytea ^ ((rowa & 7) << 4)));
    const bf16x8 hfb = *(const bf16x8*)(hb + (byteb ^ ((rowb & 7) << 4)));
    #pragma unroll
    for (int ct = 0; ct < 8; ++ct) {
      const bf16x8 bf = *(const bf16x8*)&wlds[16384 + ((kc * 8 + ct) * 64 + l) * 8];
      aa[ct] = __builtin_amdgcn_mfma_f32_16x16x32_bf16(hfa, bf, aa[ct], 0, 0, 0);
      ab[ct] = __builtin_amdgcn_mfma_f32_16x16x32_bf16(hfb, bf, ab[ct], 0, 0, 0);
    }
  }
  // ---- L2 norm (per sample group, reduce across the 16-lane li dim) ----
  #pragma unroll
  for (int grp = 0; grp < 2; ++grp) {
    f32x4* ac = grp ? ab : aa;
    float sc[4];
    #pragma unroll
    for (int rg = 0; rg < 4; ++rg) {
      float ssq = 0.f;
      #pragma unroll
      for (int ct = 0; ct < 8; ++ct) ssq += ac[ct][rg] * ac[ct][rg];
      ssq += __shfl_xor(ssq, 1);
      ssq += __shfl_xor(ssq, 2);
      ssq += __shfl_xor(ssq, 4);
      ssq += __shfl_xor(ssq, 8);
      sc[rg] = 1.f / fmaxf(sqrtf(ssq), 1e-12f);
    }
    // normalized z (bf16) -> own slab rows, linear (own H reads done; in-order DS)
    #pragma unroll
    for (int ct = 0; ct < 8; ++ct)
      #pragma unroll
      for (int rg = 0; rg < 4; ++rg)
        slab[(w * 32 + grp * 16 + 4 * g + rg) * DDIM + ct * 16 + li] =
            f2b(ac[ct][rg] * sc[rg]);
  }
  // coalesced 8 KB copy-out of own 32-row slab region (no barrier: wave-private)
  {
    const uint4* s4 = (const uint4*)&slab[(w * 32) * DDIM];
    uint4* d4 = (uint4*)(zout + (size_t)(base + w * 32) * DDIM);
    #pragma unroll
    for (int i = 0; i < 8; ++i) d4[l + 64 * i] = s4[l + 64 * i];
  }
}

// Coalesced loss, XCD-grouped: blocks with the same (typ,vl) land on one XCD
// (round-robin dispatch: xcd = blockIdx % 8) so the group's shared A-rows and
// contiguous Nb chunk are fetched into that XCD's L2 once (~11 MB total vs ~88).
__global__ __launch_bounds__(256)
void loss_kernel(const ushort_t* __restrict__ zb, float* __restrict__ out)
{
  __shared__ float sp[4], sn[4];
  const int bid = blockIdx.x;            // 800 = grp(8) x s(100)
  const int grp = bid & 7;               // XCD id under round-robin dispatch
  const int s   = bid >> 3;
  const int typ = grp >> 2;
  const int vl  = grp & 3;
  const ushort_t* A  = zb + (size_t)(typ ? ROWS_A : 0) * DDIM;
  const ushort_t* Nb = zb + (size_t)(2 * ROWS_A + (typ ? ROWS_N : 0)) * DDIM;
  const ushort_t* zs = A + (size_t)((vl * 4 + vl) * SS + s) * DDIM;
  const int t = threadIdx.x, l = t & 63, w = t >> 6;
  const int tsub = l >> 3, eg = l & 7;

  // anchor slice (16 elems) in registers, straight from global (no LDS, no barrier)
  float zr[16];
  {
    const u16x8 v0 = *(const u16x8*)(zs + eg * 16);
    const u16x8 v1 = *(const u16x8*)(zs + eg * 16 + 8);
    #pragma unroll
    for (int j = 0; j < 8; ++j) { zr[j] = b2f(v0[j]); zr[j + 8] = b2f(v1[j]); }
  }

  float pe = 0.f, ne = 0.f;
  #pragma unroll
  for (int pass = 0; pass < 5; ++pass) {
    const int tt = pass * 32 + w * 8 + tsub;
    float d = 0.f;
    bool act = (tt < 152);
    if (act) {
      const ushort_t* tp;
      if (tt < 3) {                                    // positives: other 3 slices
        const int k = tt + (tt >= vl ? 1 : 0);
        tp = A + (size_t)((k * 4 + vl) * SS + s) * DDIM;
      } else if (tt < 102) {                           // within-negs, skip self
        int t2 = tt - 3;
        if (t2 >= s) ++t2;
        tp = A + (size_t)((vl * 4 + vl) * SS + t2) * DDIM;
      } else {                                         // cross-negs
        tp = Nb + (size_t)((vl * SS + s) * NNEGS + (tt - 102)) * DDIM;
      }
      const u16x8 x0 = *(const u16x8*)(tp + eg * 16);
      const u16x8 x1 = *(const u16x8*)(tp + eg * 16 + 8);
      #pragma unroll
      for (int j = 0; j < 8; ++j) {
        d = fmaf(b2f(x0[j]), zr[j], d);
        d = fmaf(b2f(x1[j]), zr[j + 8], d);
      }
    }
    d += __shfl_xor(d, 1);
    d += __shfl_xor(d, 2);
    d += __shfl_xor(d, 4);
    const float e = act ? __expf(d * INV_TEMP) : 0.f;
    if (tt < 3) pe += e; else ne += e;
  }
  pe += __shfl_xor(pe, 8);  ne += __shfl_xor(ne, 8);
  pe += __shfl_xor(pe, 16); ne += __shfl_xor(ne, 16);
  pe += __shfl_xor(pe, 32); ne += __shfl_xor(ne, 32);
  if (l == 0) { sp[w] = pe; sn[w] = ne; }
  __syncthreads();
  if (t == 0) {
    const float P  = sp[0] + sp[1] + sp[2] + sp[3];
    const float Ng = sn[0] + sn[1] + sn[2] + sn[3];
    atomicAdd(out, -logf(P / (P + Ng)) * (1.0f / 800.0f));
  }
}

extern "C" void kernel_launch(void* const* d_in, const int* in_sizes, int n_in,
                              void* d_out, int out_size, void* d_ws, size_t ws_size,
                              hipStream_t stream) {
  const float* emb_p = (const float*)d_in[0];
  const float* emb_c = (const float*)d_in[1];
  const float* W1    = (const float*)d_in[2];
  const float* b1    = (const float*)d_in[3];
  const float* W2    = (const float*)d_in[4];
  const float* b2    = (const float*)d_in[5];
  const void*  idx_p  = d_in[6];
  const void*  idx_c  = d_in[7];
  const void*  nidx_p = d_in[8];
  const void*  nidx_c = d_in[9];
  float* out = (float*)d_out;
  ushort_t* zrows = (ushort_t*)d_ws;

  proj_kernel<<<NBLK, 512, 0, stream>>>(
      emb_p, emb_c, W1, b1, W2, b2, idx_p, idx_c, nidx_p, nidx_c, zrows, out);
  loss_kernel<<<800, 256, 0, stream>>>(zrows, out);
}